// Round 3
// baseline (501.728 us; speedup 1.0000x reference)
//
#include <hip/hip_runtime.h>
#include <hip/hip_bf16.h>

#define GROUPS 16
#define BSZ    8192
#define CHN    256
#define COLH   128
#define BSTR   133   // LDS dwords per B column (128 + 5, odd -> <=2-way banks)

using f32x4  = __attribute__((ext_vector_type(4))) float;
using bf16x8 = __attribute__((ext_vector_type(8))) __bf16;

static __device__ __forceinline__ unsigned short f32_bf16(float f) {
    unsigned int u = __builtin_bit_cast(unsigned int, f);
    u = (u + 0x7FFFu + ((u >> 16) & 1u)) >> 16;   // RNE
    return (unsigned short)u;
}
static __device__ __forceinline__ unsigned int pack_bf16x2(float lo, float hi) {
    return (unsigned int)f32_bf16(lo) | ((unsigned int)f32_bf16(hi) << 16);
}
static __device__ __forceinline__ bf16x8 pack8(float4 u, float4 v) {
    uint4 d;
    d.x = pack_bf16x2(u.x, u.y);
    d.y = pack_bf16x2(u.z, u.w);
    d.z = pack_bf16x2(v.x, v.y);
    d.w = pack_bf16x2(v.z, v.w);
    return __builtin_bit_cast(bf16x8, d);
}

// ---------------------------------------------------------------------------
// Kernel B: compose M = H_0 H_1 ... H_255 per group, row-parallel (unchanged).
// Output: Mt[g][c][n] = M[n][c]  (bf16), n = k-dim for the GEMM.
// ---------------------------------------------------------------------------
__global__ __launch_bounds__(256) void compose_m(const float* __restrict__ weight,
                                                 unsigned short* __restrict__ Mt) {
    __shared__ float wbuf[16 * 260];
    __shared__ float coefbuf[16];

    const int t    = threadIdx.x;
    const int g    = blockIdx.x >> 4;
    const int r0   = (blockIdx.x & 15) * 16;
    const int lane = t & 15;
    const int rg   = (t >> 4) & 3;
    const int wave = t >> 6;
    const int r    = r0 + wave * 4 + rg;

    float4 m4[4];
#pragma unroll
    for (int j = 0; j < 4; ++j) {
        const int cb = 4 * lane + 64 * j;
        m4[j].x = (cb + 0 == r) ? 1.0f : 0.0f;
        m4[j].y = (cb + 1 == r) ? 1.0f : 0.0f;
        m4[j].z = (cb + 2 == r) ? 1.0f : 0.0f;
        m4[j].w = (cb + 3 == r) ? 1.0f : 0.0f;
    }

    const float* wg = weight + (size_t)g * CHN * CHN;
    const int e16 = t & 15;
    const int nb  = t >> 4;

    float ld[16];
#pragma unroll
    for (int k = 0; k < 16; ++k)
        ld[k] = wg[(nb + 16 * k) * CHN + e16];

    for (int iw = 0; iw < 16; ++iw) {
        __syncthreads();
#pragma unroll
        for (int k = 0; k < 16; ++k)
            wbuf[e16 * 260 + nb + 16 * k] = ld[k];
        __syncthreads();
        if (iw < 15) {
            const int i0 = (iw + 1) * 16;
#pragma unroll
            for (int k = 0; k < 16; ++k)
                ld[k] = wg[(nb + 16 * k) * CHN + i0 + e16];
        }
        {
            const int e = t >> 4;
            float s = 0.0f;
#pragma unroll
            for (int k = 0; k < 16; ++k) {
                const float w = wbuf[e * 260 + lane + 16 * k];
                s += w * w;
            }
            s += __shfl_xor(s, 1);
            s += __shfl_xor(s, 2);
            s += __shfl_xor(s, 4);
            s += __shfl_xor(s, 8);
            if (lane == 0) coefbuf[e] = 2.0f / s;
        }
        __syncthreads();
#pragma unroll
        for (int e = 0; e < 16; ++e) {
            float4 w4[4];
#pragma unroll
            for (int j = 0; j < 4; ++j)
                w4[j] = *(const float4*)&wbuf[e * 260 + 4 * lane + 64 * j];
            float p0 = m4[0].x * w4[0].x + m4[0].y * w4[0].y +
                       m4[0].z * w4[0].z + m4[0].w * w4[0].w;
            float p1 = m4[1].x * w4[1].x + m4[1].y * w4[1].y +
                       m4[1].z * w4[1].z + m4[1].w * w4[1].w;
            float p2 = m4[2].x * w4[2].x + m4[2].y * w4[2].y +
                       m4[2].z * w4[2].z + m4[2].w * w4[2].w;
            float p3 = m4[3].x * w4[3].x + m4[3].y * w4[3].y +
                       m4[3].z * w4[3].z + m4[3].w * w4[3].w;
            float p = (p0 + p1) + (p2 + p3);
            p += __shfl_xor(p, 1);
            p += __shfl_xor(p, 2);
            p += __shfl_xor(p, 4);
            p += __shfl_xor(p, 8);
            const float s = coefbuf[e] * p;
#pragma unroll
            for (int j = 0; j < 4; ++j) {
                m4[j].x -= s * w4[j].x;
                m4[j].y -= s * w4[j].y;
                m4[j].z -= s * w4[j].z;
                m4[j].w -= s * w4[j].w;
            }
        }
    }

    unsigned short* mg = Mt + (size_t)g * CHN * CHN;
#pragma unroll
    for (int j = 0; j < 4; ++j) {
        const int cb = 4 * lane + 64 * j;
        mg[(size_t)(cb + 0) * CHN + r] = f32_bf16(m4[j].x);
        mg[(size_t)(cb + 1) * CHN + r] = f32_bf16(m4[j].y);
        mg[(size_t)(cb + 2) * CHN + r] = f32_bf16(m4[j].z);
        mg[(size_t)(cb + 3) * CHN + r] = f32_bf16(m4[j].w);
    }
}

// ---------------------------------------------------------------------------
// Kernel C (R3): B resident in LDS (staged ONCE, odd stride -> conflict-free
// frag reads), then a barrier-free streaming loop. Wave tile 16 rows x 128
// cols -> acc only 32 regs, 2 global loads per K-chunk, register-level
// double-buffer. 2 blocks/CU (__launch_bounds__(512,4)), 16 waves/CU.
// Grid: g(16) x rowchunk(16) x colhalf(2), colhalf fastest so the sibling
// block's x re-read hits L3.
// ---------------------------------------------------------------------------
__global__ __launch_bounds__(512, 4) void gemm_bcol(const float* __restrict__ x,
                                                    const unsigned short* __restrict__ Mt,
                                                    float* __restrict__ out) {
    __shared__ unsigned int bsh[COLH * BSTR];   // 68096 B

    const int t        = threadIdx.x;
    const int chalf    = blockIdx.x & 1;
    const int rowchunk = (blockIdx.x >> 1) & 15;
    const int g        = blockIdx.x >> 5;

    // stage B once: 128 cols x 256 k (bf16), k-contiguous dwordx4 loads
    {
        const int col = t >> 2;   // 0..127
        const int kq  = t & 3;    // 0..3, 8 uint4 each
        const uint4* src = (const uint4*)(Mt + ((size_t)g * CHN + chalf * COLH + col) * CHN);
#pragma unroll
        for (int s = 0; s < 8; ++s) {
            const uint4 v = src[kq * 8 + s];
            unsigned int* d = &bsh[col * BSTR + (kq * 8 + s) * 4];
            d[0] = v.x; d[1] = v.y; d[2] = v.z; d[3] = v.w;
        }
    }
    __syncthreads();   // the only barrier

    const int w  = t >> 6;
    const int l  = t & 63;
    const int lm = l & 15;
    const int q  = l >> 4;

    const float* xg = x   + (size_t)g * BSZ * CHN;
    float*       og = out + (size_t)g * BSZ * CHN;

    for (int s = 0; s < 4; ++s) {
        const int row0 = rowchunk * 512 + s * 128 + w * 16;
        const float* xp = xg + (size_t)(row0 + lm) * CHN + q * 8;

        f32x4 acc[8];
#pragma unroll
        for (int ni = 0; ni < 8; ++ni)
            acc[ni] = (f32x4){0.f, 0.f, 0.f, 0.f};

        float4 c0 = *(const float4*)(xp);
        float4 c1 = *(const float4*)(xp + 4);
#pragma unroll
        for (int kc = 0; kc < 8; ++kc) {
            const int kn = (kc < 7) ? kc + 1 : kc;   // last iter re-reads (L1 hit)
            const float4 n0 = *(const float4*)(xp + kn * 32);
            const float4 n1 = *(const float4*)(xp + kn * 32 + 4);
            const bf16x8 a = pack8(c0, c1);
#pragma unroll
            for (int ni = 0; ni < 8; ++ni) {
                const unsigned int* bp = &bsh[(ni * 16 + lm) * BSTR + kc * 16 + q * 4];
                uint4 u;
                u.x = bp[0]; u.y = bp[1]; u.z = bp[2]; u.w = bp[3];
                acc[ni] = __builtin_amdgcn_mfma_f32_16x16x32_bf16(
                    a, __builtin_bit_cast(bf16x8, u), acc[ni], 0, 0, 0);
            }
            c0 = n0; c1 = n1;
        }

        // D layout: col = lane&15, row = (lane>>4)*4 + reg
        float* ob = og + (size_t)(row0 + q * 4) * CHN + chalf * COLH + lm;
#pragma unroll
        for (int ni = 0; ni < 8; ++ni)
#pragma unroll
            for (int reg = 0; reg < 4; ++reg)
                ob[(size_t)reg * CHN + ni * 16] = acc[ni][reg];
    }
}

extern "C" void kernel_launch(void* const* d_in, const int* in_sizes, int n_in,
                              void* d_out, int out_size, void* d_ws, size_t ws_size,
                              hipStream_t stream) {
    const float* x = (const float*)d_in[0];
    const float* w = (const float*)d_in[1];
    float* out = (float*)d_out;
    unsigned short* Mt = (unsigned short*)d_ws;   // 16*256*256 bf16 = 2 MB

    hipLaunchKernelGGL(compose_m, dim3(GROUPS * 16),     dim3(256), 0, stream, w, Mt);
    hipLaunchKernelGGL(gemm_bcol, dim3(GROUPS * 16 * 2), dim3(512), 0, stream, x, Mt, out);
}

// Round 4
// 349.870 us; speedup vs baseline: 1.4340x; 1.4340x over previous
//
#include <hip/hip_runtime.h>
#include <hip/hip_bf16.h>

#define GROUPS 16
#define BSZ    8192
#define CHN    256
#define BSTR   133   // LDS dwords per B column: 128 + 5; 133 % 32 == 5 -> <=2-way banks

using f32x4  = __attribute__((ext_vector_type(4))) float;
using bf16x8 = __attribute__((ext_vector_type(8))) __bf16;

static __device__ __forceinline__ unsigned short f32_bf16(float f) {
    unsigned int u = __builtin_bit_cast(unsigned int, f);
    u = (u + 0x7FFFu + ((u >> 16) & 1u)) >> 16;   // RNE
    return (unsigned short)u;
}
static __device__ __forceinline__ unsigned int pack_bf16x2(float lo, float hi) {
    return (unsigned int)f32_bf16(lo) | ((unsigned int)f32_bf16(hi) << 16);
}
static __device__ __forceinline__ bf16x8 pack8(float4 u, float4 v) {
    uint4 d;
    d.x = pack_bf16x2(u.x, u.y);
    d.y = pack_bf16x2(u.z, u.w);
    d.z = pack_bf16x2(v.x, v.y);
    d.w = pack_bf16x2(v.z, v.w);
    return __builtin_bit_cast(bf16x8, d);
}

// ---------------------------------------------------------------------------
// Kernel B: compose M = H_0 H_1 ... H_255 per group, row-parallel (unchanged).
// Output: Mt[g][c][n] = M[n][c]  (bf16), n = k-dim for the GEMM.
// ---------------------------------------------------------------------------
__global__ __launch_bounds__(256) void compose_m(const float* __restrict__ weight,
                                                 unsigned short* __restrict__ Mt) {
    __shared__ float wbuf[16 * 260];
    __shared__ float coefbuf[16];

    const int t    = threadIdx.x;
    const int g    = blockIdx.x >> 4;
    const int r0   = (blockIdx.x & 15) * 16;
    const int lane = t & 15;
    const int rg   = (t >> 4) & 3;
    const int wave = t >> 6;
    const int r    = r0 + wave * 4 + rg;

    float4 m4[4];
#pragma unroll
    for (int j = 0; j < 4; ++j) {
        const int cb = 4 * lane + 64 * j;
        m4[j].x = (cb + 0 == r) ? 1.0f : 0.0f;
        m4[j].y = (cb + 1 == r) ? 1.0f : 0.0f;
        m4[j].z = (cb + 2 == r) ? 1.0f : 0.0f;
        m4[j].w = (cb + 3 == r) ? 1.0f : 0.0f;
    }

    const float* wg = weight + (size_t)g * CHN * CHN;
    const int e16 = t & 15;
    const int nb  = t >> 4;

    float ld[16];
#pragma unroll
    for (int k = 0; k < 16; ++k)
        ld[k] = wg[(nb + 16 * k) * CHN + e16];

    for (int iw = 0; iw < 16; ++iw) {
        __syncthreads();
#pragma unroll
        for (int k = 0; k < 16; ++k)
            wbuf[e16 * 260 + nb + 16 * k] = ld[k];
        __syncthreads();
        if (iw < 15) {
            const int i0 = (iw + 1) * 16;
#pragma unroll
            for (int k = 0; k < 16; ++k)
                ld[k] = wg[(nb + 16 * k) * CHN + i0 + e16];
        }
        {
            const int e = t >> 4;
            float s = 0.0f;
#pragma unroll
            for (int k = 0; k < 16; ++k) {
                const float w = wbuf[e * 260 + lane + 16 * k];
                s += w * w;
            }
            s += __shfl_xor(s, 1);
            s += __shfl_xor(s, 2);
            s += __shfl_xor(s, 4);
            s += __shfl_xor(s, 8);
            if (lane == 0) coefbuf[e] = 2.0f / s;
        }
        __syncthreads();
#pragma unroll
        for (int e = 0; e < 16; ++e) {
            float4 w4[4];
#pragma unroll
            for (int j = 0; j < 4; ++j)
                w4[j] = *(const float4*)&wbuf[e * 260 + 4 * lane + 64 * j];
            float p0 = m4[0].x * w4[0].x + m4[0].y * w4[0].y +
                       m4[0].z * w4[0].z + m4[0].w * w4[0].w;
            float p1 = m4[1].x * w4[1].x + m4[1].y * w4[1].y +
                       m4[1].z * w4[1].z + m4[1].w * w4[1].w;
            float p2 = m4[2].x * w4[2].x + m4[2].y * w4[2].y +
                       m4[2].z * w4[2].z + m4[2].w * w4[2].w;
            float p3 = m4[3].x * w4[3].x + m4[3].y * w4[3].y +
                       m4[3].z * w4[3].z + m4[3].w * w4[3].w;
            float p = (p0 + p1) + (p2 + p3);
            p += __shfl_xor(p, 1);
            p += __shfl_xor(p, 2);
            p += __shfl_xor(p, 4);
            p += __shfl_xor(p, 8);
            const float s = coefbuf[e] * p;
#pragma unroll
            for (int j = 0; j < 4; ++j) {
                m4[j].x -= s * w4[j].x;
                m4[j].y -= s * w4[j].y;
                m4[j].z -= s * w4[j].z;
                m4[j].w -= s * w4[j].w;
            }
        }
    }

    unsigned short* mg = Mt + (size_t)g * CHN * CHN;
#pragma unroll
    for (int j = 0; j < 4; ++j) {
        const int cb = 4 * lane + 64 * j;
        mg[(size_t)(cb + 0) * CHN + r] = f32_bf16(m4[j].x);
        mg[(size_t)(cb + 1) * CHN + r] = f32_bf16(m4[j].y);
        mg[(size_t)(cb + 2) * CHN + r] = f32_bf16(m4[j].z);
        mg[(size_t)(cb + 3) * CHN + r] = f32_bf16(m4[j].w);
    }
}

// ---------------------------------------------------------------------------
// Kernel C (R4): FULL M (256 cols x 256 k bf16) resident in LDS (133 KB,
// staged once, stride 133 dwords -> <=2-way banks = free). Block = 1024 thr
// = 16 waves = whole CU (1 block/CU, 4 waves/SIMD). Each wave: 2 strips of
// 16 rows x 256 cols; acc = 64 regs. NO barriers in the main loop; x loads
// register double-buffered (2 outstanding 1KB wave-loads -> 32KB in
// flight/CU >> ~9KB BW-delay product). Full-row ownership -> x read once,
// stores merge to full lines.
// Grid: 16 groups x 16 row-chunks (512 rows each) = 256 blocks.
// ---------------------------------------------------------------------------
__global__ __launch_bounds__(1024, 4) void gemm_full(const float* __restrict__ x,
                                                     const unsigned short* __restrict__ Mt,
                                                     float* __restrict__ out) {
    __shared__ unsigned int bsh[CHN * BSTR];   // 136192 B

    const int t        = threadIdx.x;
    const int rowchunk = blockIdx.x & 15;
    const int g        = blockIdx.x >> 4;

    // stage all of M[g]: 256 cols x 256 k (bf16), k-contiguous dwordx4 loads
    {
        const int col = t >> 2;   // 0..255
        const int kq  = t & 3;    // 0..3
        const uint4* src = (const uint4*)(Mt + ((size_t)g * CHN + col) * CHN);
#pragma unroll
        for (int s = 0; s < 8; ++s) {
            const uint4 v = src[kq * 8 + s];
            unsigned int* d = &bsh[col * BSTR + (kq * 8 + s) * 4];
            d[0] = v.x; d[1] = v.y; d[2] = v.z; d[3] = v.w;
        }
    }
    __syncthreads();   // the only barrier

    const int w  = t >> 6;    // wave 0..15
    const int l  = t & 63;
    const int lm = l & 15;
    const int q  = l >> 4;

    const int row0 = rowchunk * 512 + w * 16;   // strip s adds s*256
    const float* xg = x   + (size_t)g * BSZ * CHN;
    float*       og = out + (size_t)g * BSZ * CHN;
    const float* xp0 = xg + (size_t)(row0 + lm) * CHN + q * 8;

    float4 c0 = *(const float4*)(xp0);
    float4 c1 = *(const float4*)(xp0 + 4);

#pragma unroll
    for (int s = 0; s < 2; ++s) {
        const float* xp = xp0 + (size_t)s * 256 * CHN;
        const float* xn = xp + (size_t)256 * CHN;   // next strip (s==1: unused re-read)

        f32x4 acc[16];
#pragma unroll
        for (int ni = 0; ni < 16; ++ni)
            acc[ni] = (f32x4){0.f, 0.f, 0.f, 0.f};

#pragma unroll
        for (int kc = 0; kc < 8; ++kc) {
            // prefetch next chunk (or next strip's first chunk)
            const float* np = (kc < 7) ? (xp + (kc + 1) * 32) : ((s < 1) ? xn : xp);
            const float4 n0 = *(const float4*)(np);
            const float4 n1 = *(const float4*)(np + 4);
            const bf16x8 a = pack8(c0, c1);
#pragma unroll
            for (int ni = 0; ni < 16; ++ni) {
                const unsigned int* bp = &bsh[(ni * 16 + lm) * BSTR + kc * 16 + q * 4];
                uint4 u;
                u.x = bp[0]; u.y = bp[1]; u.z = bp[2]; u.w = bp[3];
                acc[ni] = __builtin_amdgcn_mfma_f32_16x16x32_bf16(
                    a, __builtin_bit_cast(bf16x8, u), acc[ni], 0, 0, 0);
            }
            c0 = n0; c1 = n1;
        }

        // D layout: col = lane&15 (+16*ni), row = (lane>>4)*4 + reg
        float* ob = og + (size_t)(row0 + s * 256 + q * 4) * CHN + lm;
#pragma unroll
        for (int ni = 0; ni < 16; ++ni)
#pragma unroll
            for (int reg = 0; reg < 4; ++reg)
                ob[(size_t)reg * CHN + ni * 16] = acc[ni][reg];
    }
}

extern "C" void kernel_launch(void* const* d_in, const int* in_sizes, int n_in,
                              void* d_out, int out_size, void* d_ws, size_t ws_size,
                              hipStream_t stream) {
    const float* x = (const float*)d_in[0];
    const float* w = (const float*)d_in[1];
    float* out = (float*)d_out;
    unsigned short* Mt = (unsigned short*)d_ws;   // 16*256*256 bf16 = 2 MB

    hipLaunchKernelGGL(compose_m, dim3(GROUPS * 16), dim3(256),  0, stream, w, Mt);
    hipLaunchKernelGGL(gemm_full, dim3(GROUPS * 16), dim3(1024), 0, stream, x, Mt, out);
}